// Round 9
// baseline (67.469 us; speedup 1.0000x reference)
//
#include <hip/hip_runtime.h>
#include <hip/hip_bf16.h>

#define DD 256
#define NN 8192
#define B_ROWS 4096
#define NRG 64                 // row-groups of 128
#define NCJ 128                // col-chunks of 64
#define NBLK 4160              // sum_{rg=0}^{63} (128 - 2*rg)
#define M_FIX 160.0f           // fixed softmax offset (exp2 domain)
#define SCALE 1.6986436f       // sqrt(2*log2(e)): sim lands in exp2 domain
#define LN2 0.69314718055994531f

typedef __attribute__((ext_vector_type(8))) short bf16x8;
typedef __attribute__((ext_vector_type(4))) float f32x4;

__device__ __forceinline__ unsigned short f2bf(float f) {
    unsigned int x = __float_as_uint(f);
    x += 0x7fffu + ((x >> 16) & 1u);   // RNE
    return (unsigned short)(x >> 16);
}
__device__ __forceinline__ float bf2f(unsigned short u) {
    return __uint_as_float((unsigned int)u << 16);
}
__device__ __forceinline__ float exp2_raw(float x) {
    float r; asm("v_exp_f32 %0, %1" : "=v"(r) : "v"(x)); return r;
}
__device__ __forceinline__ void gload16(const unsigned short* g, unsigned short* l) {
    __builtin_amdgcn_global_load_lds(
        (const __attribute__((address_space(1))) void*)g,
        (__attribute__((address_space(3))) void*)l, 16, 0, 0);
}

// ------------- Kernel 1: fused cast(z*SCALE -> bf16) + pos dot (fp32) --------
__global__ void cast_pos_kernel(const float* __restrict__ zi, const float* __restrict__ zj,
                                unsigned short* __restrict__ zb, float* __restrict__ pos) {
    const int w = threadIdx.x >> 6;
    const int l = threadIdx.x & 63;
    const int r = blockIdx.x * 4 + w;                       // grid 1024 -> r < 4096
    const float4 a = ((const float4*)(zi + (size_t)r * DD))[l];
    const float4 b = ((const float4*)(zj + (size_t)r * DD))[l];
    float d = a.x * b.x + a.y * b.y + a.z * b.z + a.w * b.w;
    #pragma unroll
    for (int off = 32; off > 0; off >>= 1) d += __shfl_down(d, off, 64);
    if (l == 0) pos[r] = 2.0f * d;                          // natural-domain pos logit
    ushort4 oa, ob;
    oa.x = f2bf(a.x * SCALE); oa.y = f2bf(a.y * SCALE);
    oa.z = f2bf(a.z * SCALE); oa.w = f2bf(a.w * SCALE);
    ob.x = f2bf(b.x * SCALE); ob.y = f2bf(b.y * SCALE);
    ob.z = f2bf(b.z * SCALE); ob.w = f2bf(b.w * SCALE);
    ((ushort4*)(zb + (size_t)r * DD))[l] = oa;
    ((ushort4*)(zb + (size_t)(r + B_ROWS) * DD))[l] = ob;
}

// ------------- Kernel 2: symmetric Gram + fixed-M exp2 sums ------------------
// grid: 4160 rect blocks (rg: 128 rows) x (cj: 64 cols), cj >= 2*rg.
// cj in {2rg, 2rg+1}: diagonal square halves — row-sums only, i==j masked.
// cj >= 2rg+2: strictly above diagonal — row-sums + mirror col-sums -> slot 2rg.
// block: 256 thr = 4 waves; wave owns 32 rows: aF[2][8] = 64 VGPR (R=2 reuse).
// REGISTER BUDGET IS THE POINT: total ~110 VGPR fits __launch_bounds__(256,4)
// without spill (R=4 variants spilled A-frags to scratch every iteration:
// FETCH 24MB / WRITE 23MB of spill traffic, rounds 3/5/6/8).
// 32 KB panel (64 cols x 256 K) staged once in fragment order, one barrier.
// PT bf16 [128][NN]: row partials at PT[cj][row], mirror at PT[2rg][col].
__global__ __launch_bounds__(256, 4) void simlse_kernel(const unsigned short* __restrict__ zb,
                                                        unsigned short* __restrict__ PT) {
    __shared__ unsigned short tile[32 * 512];               // 32 KB: 32 slots x 1 KB
    const int tid = threadIdx.x;
    const int w  = tid >> 6;        // 0..3
    const int l  = tid & 63;
    const int lg = l >> 4;          // 0..3
    const int lr = l & 15;          // 0..15

    // XCD-aware bijective swizzle (4160 = 8 x 520)
    const int wg = ((int)blockIdx.x & 7) * (NBLK / 8) + ((int)blockIdx.x >> 3);
    int b = wg, rg = 0;
    while (b >= NCJ - 2 * rg) { b -= NCJ - 2 * rg; ++rg; }
    const int cj = 2 * rg + b;
    const bool mirror = (cj >= 2 * rg + 2);                 // block-uniform
    const int rbase = rg * 128 + w * 32;
    const int cbase = cj * 64;
    const int ri_u0 = rg * 8 + w * 2;                       // wave's first row 16-tile

    // stage panel: 32 slots (slot = sl*8+ks); wave w stages col-16-tile sl=w
    #pragma unroll
    for (int jj = 0; jj < 8; ++jj)
        gload16(zb + (size_t)(cbase + w * 16 + lr) * DD + jj * 32 + lg * 8,
                tile + (w * 8 + jj) * 512);

    // A fragments: 2 row-tiles x 8 k-slices (64 VGPR)
    bf16x8 aF[2][8];
    #pragma unroll
    for (int rt = 0; rt < 2; ++rt) {
        const unsigned short* ap = zb + (size_t)(rbase + rt * 16 + lr) * DD + lg * 8;
        #pragma unroll
        for (int ks = 0; ks < 8; ++ks) aF[rt][ks] = *(const bf16x8*)(ap + ks * 32);
    }

    float rs[2][4];
    #pragma unroll
    for (int rt = 0; rt < 2; ++rt)
        #pragma unroll
        for (int j = 0; j < 4; ++j) rs[rt][j] = 0.f;
    float cs[4];
    #pragma unroll
    for (int sl = 0; sl < 4; ++sl) cs[sl] = 0.f;

    __syncthreads();                                        // single staging drain

    #pragma unroll
    for (int sl = 0; sl < 4; ++sl) {
        f32x4 acc[2];
        acc[0] = (f32x4){0.f, 0.f, 0.f, 0.f};
        acc[1] = (f32x4){0.f, 0.f, 0.f, 0.f};
        #pragma unroll
        for (int ks = 0; ks < 8; ++ks) {
            bf16x8 bF = *(const bf16x8*)(tile + (sl * 8 + ks) * 512 + l * 8);
            acc[0] = __builtin_amdgcn_mfma_f32_16x16x32_bf16(aF[0][ks], bF, acc[0], 0, 0, 0);
            acc[1] = __builtin_amdgcn_mfma_f32_16x16x32_bf16(aF[1][ks], bF, acc[1], 0, 0, 0);
        }
        const int ci_u = cj * 4 + sl;
        #pragma unroll
        for (int rt = 0; rt < 2; ++rt) {
            const bool dt = (!mirror) && (ri_u0 + rt == ci_u);
            #pragma unroll
            for (int j = 0; j < 4; ++j) {
                float e = exp2_raw(acc[rt][j] - M_FIX);
                if (dt && (lr == lg * 4 + j)) e = 0.f;      // mask i==j
                rs[rt][j] += e;
                cs[sl] += e;
            }
        }
    }

    // row sums: reduce over 16 lanes sharing lg; lr==0 lanes write
    #pragma unroll
    for (int rt = 0; rt < 2; ++rt)
        #pragma unroll
        for (int j = 0; j < 4; ++j) {
            float v = rs[rt][j];
            v += __shfl_xor(v, 1, 64);
            v += __shfl_xor(v, 2, 64);
            v += __shfl_xor(v, 4, 64);
            v += __shfl_xor(v, 8, 64);
            rs[rt][j] = v;
        }
    if (lr == 0) {
        #pragma unroll
        for (int rt = 0; rt < 2; ++rt)
            #pragma unroll
            for (int j = 0; j < 4; ++j)
                PT[(size_t)cj * NN + rbase + rt * 16 + lg * 4 + j] = f2bf(rs[rt][j]);
    }

    // mirror column sums -> slot 2*rg (strictly-above blocks only; block-uniform)
    if (mirror) {
        #pragma unroll
        for (int sl = 0; sl < 4; ++sl) {
            float v = cs[sl];
            v += __shfl_xor(v, 16, 64);
            v += __shfl_xor(v, 32, 64);
            cs[sl] = v;                                     // sum over wave's 32 rows
        }
        __syncthreads();                                    // all tile reads done
        float* red = (float*)tile;                          // [4][64] floats = 1 KB
        if (lg == 0) {
            #pragma unroll
            for (int sl = 0; sl < 4; ++sl) red[w * 64 + sl * 16 + lr] = cs[sl];
        }
        __syncthreads();
        if (tid < 64) {
            const float v = red[tid] + red[64 + tid] + red[128 + tid] + red[192 + tid];
            PT[(size_t)(2 * rg) * NN + cbase + tid] = f2bf(v);
        }
    }
}

// ------------- Kernel 3: per-row masked-slot sum + pos subtraction -----------
// slot s valid for row r (rg = r>>7) iff (s >= 2rg) || s even — provably the
// exact set of slots simlse writes for this row. Branch-free select.
__global__ __launch_bounds__(128) void rowmerge_kernel(const unsigned short* __restrict__ PT,
                                                       const float* __restrict__ pos,
                                                       float* __restrict__ partial) {
    const int r = blockIdx.x * 128 + threadIdx.x;           // grid 64 -> r < 8192
    const int rg = r >> 7;
    float S = 0.f;
    #pragma unroll
    for (int s = 0; s < NCJ; ++s) {
        const float v = bf2f(PT[(size_t)s * NN + r]);
        const bool valid = (s >= 2 * rg) || ((s & 1) == 0);
        S += valid ? v : 0.f;
    }
    float val = M_FIX * LN2 + logf(S);                      // natural-domain lse
    if (r < B_ROWS) val -= 2.0f * pos[r];                   // both halves' pos
    __shared__ float red[128];
    red[threadIdx.x] = val;
    __syncthreads();
    for (int st = 64; st > 0; st >>= 1) {
        if (threadIdx.x < st) red[threadIdx.x] += red[threadIdx.x + st];
        __syncthreads();
    }
    if (threadIdx.x == 0) partial[blockIdx.x] = red[0];
}

// ------------- Kernel 4: final scalar ----------------------------------------
__global__ void final_kernel(const float* __restrict__ partial, float* __restrict__ out) {
    float v = partial[threadIdx.x];                         // block = 64 = grid of k3
    #pragma unroll
    for (int off = 32; off > 0; off >>= 1) v += __shfl_down(v, off, 64);
    if (threadIdx.x == 0) out[0] = v / (8192.f * 8192.f);
}

extern "C" void kernel_launch(void* const* d_in, const int* in_sizes, int n_in,
                              void* d_out, int out_size, void* d_ws, size_t ws_size,
                              hipStream_t stream) {
    const float* zi = (const float*)d_in[0];
    const float* zj = (const float*)d_in[1];
    float* out = (float*)d_out;
    char* ws = (char*)d_ws;

    unsigned short* zb = (unsigned short*)ws;                         // 4 MB
    unsigned short* PT = (unsigned short*)(ws + (size_t)NN * DD * 2); // 2 MB bf16 [128][NN]
    float* pos     = (float*)(ws + (size_t)NN * DD * 2 + (size_t)NCJ * NN * 2);  // 16 KB
    float* partial = pos + B_ROWS;                                    // 256 B

    hipLaunchKernelGGL(cast_pos_kernel, dim3(B_ROWS / 4), dim3(256), 0, stream, zi, zj, zb, pos);
    hipLaunchKernelGGL(simlse_kernel,   dim3(NBLK), dim3(256), 0, stream, zb, PT);
    hipLaunchKernelGGL(rowmerge_kernel, dim3(NN / 128), dim3(128), 0, stream, PT, pos, partial);
    hipLaunchKernelGGL(final_kernel,    dim3(1), dim3(64), 0, stream, partial, out);
}

// Round 10
// 67.412 us; speedup vs baseline: 1.0008x; 1.0008x over previous
//
#include <hip/hip_runtime.h>
#include <hip/hip_bf16.h>

#define DD 256
#define NN 8192
#define B_ROWS 4096
#define NRG 64                 // row-groups of 128
#define NCJ 128                // col-chunks of 64
#define NBLK 4160              // sum_{rg=0}^{63} (128 - 2*rg)
#define M_FIX 160.0f           // fixed softmax offset (exp2 domain)
#define SCALE 1.6986436f       // sqrt(2*log2(e)): sim lands in exp2 domain
#define LN2 0.69314718055994531f

typedef __attribute__((ext_vector_type(8))) short bf16x8;
typedef __attribute__((ext_vector_type(4))) float f32x4;

__device__ __forceinline__ unsigned short f2bf(float f) {
    unsigned int x = __float_as_uint(f);
    x += 0x7fffu + ((x >> 16) & 1u);   // RNE
    return (unsigned short)(x >> 16);
}
__device__ __forceinline__ float bf2f(unsigned short u) {
    return __uint_as_float((unsigned int)u << 16);
}
__device__ __forceinline__ float exp2_raw(float x) {
    float r; asm("v_exp_f32 %0, %1" : "=v"(r) : "v"(x)); return r;
}
__device__ __forceinline__ void gload16(const unsigned short* g, unsigned short* l) {
    __builtin_amdgcn_global_load_lds(
        (const __attribute__((address_space(1))) void*)g,
        (__attribute__((address_space(3))) void*)l, 16, 0, 0);
}
// Pin a 16B fragment into VGPRs: opaque asm def -> compiler CANNOT rematerialize
// the originating load inside the loop (round-9 lesson: VGPR_Count=56 proved
// aF was being re-loaded from L2 per MFMA, serializing everything at ~200cyc).
__device__ __forceinline__ void pin16(bf16x8& v) {
    f32x4 t = __builtin_bit_cast(f32x4, v);
    asm volatile("" : "+v"(t));
    v = __builtin_bit_cast(bf16x8, t);
}

// ------------- Kernel 1: fused cast(z*SCALE -> bf16) + pos dot (fp32) --------
__global__ void cast_pos_kernel(const float* __restrict__ zi, const float* __restrict__ zj,
                                unsigned short* __restrict__ zb, float* __restrict__ pos) {
    const int w = threadIdx.x >> 6;
    const int l = threadIdx.x & 63;
    const int r = blockIdx.x * 4 + w;                       // grid 1024 -> r < 4096
    const float4 a = ((const float4*)(zi + (size_t)r * DD))[l];
    const float4 b = ((const float4*)(zj + (size_t)r * DD))[l];
    float d = a.x * b.x + a.y * b.y + a.z * b.z + a.w * b.w;
    #pragma unroll
    for (int off = 32; off > 0; off >>= 1) d += __shfl_down(d, off, 64);
    if (l == 0) pos[r] = 2.0f * d;                          // natural-domain pos logit
    ushort4 oa, ob;
    oa.x = f2bf(a.x * SCALE); oa.y = f2bf(a.y * SCALE);
    oa.z = f2bf(a.z * SCALE); oa.w = f2bf(a.w * SCALE);
    ob.x = f2bf(b.x * SCALE); ob.y = f2bf(b.y * SCALE);
    ob.z = f2bf(b.z * SCALE); ob.w = f2bf(b.w * SCALE);
    ((ushort4*)(zb + (size_t)r * DD))[l] = oa;
    ((ushort4*)(zb + (size_t)(r + B_ROWS) * DD))[l] = ob;
}

// ------------- Kernel 2: symmetric Gram + fixed-M exp2 sums ------------------
// Identical to the round-9 passing kernel EXCEPT the A-fragments are pinned
// into VGPRs after load (see pin16). Geometry: 4160 rect blocks (rg: 128 rows)
// x (cj: 64 cols), cj >= 2*rg; 256 thr = 4 waves; wave owns 32 rows
// (aF[2][8] = 64 VGPR, R=2 reuse); 32 KB B-panel staged once, one barrier.
// PT bf16 [128][NN]: row partials at PT[cj][row], mirror at PT[2rg][col].
__global__ __launch_bounds__(256, 4) void simlse_kernel(const unsigned short* __restrict__ zb,
                                                        unsigned short* __restrict__ PT) {
    __shared__ unsigned short tile[32 * 512];               // 32 KB: 32 slots x 1 KB
    const int tid = threadIdx.x;
    const int w  = tid >> 6;        // 0..3
    const int l  = tid & 63;
    const int lg = l >> 4;          // 0..3
    const int lr = l & 15;          // 0..15

    // XCD-aware bijective swizzle (4160 = 8 x 520)
    const int wg = ((int)blockIdx.x & 7) * (NBLK / 8) + ((int)blockIdx.x >> 3);
    int b = wg, rg = 0;
    while (b >= NCJ - 2 * rg) { b -= NCJ - 2 * rg; ++rg; }
    const int cj = 2 * rg + b;
    const bool mirror = (cj >= 2 * rg + 2);                 // block-uniform
    const int rbase = rg * 128 + w * 32;
    const int cbase = cj * 64;
    const int ri_u0 = rg * 8 + w * 2;                       // wave's first row 16-tile

    // stage panel: 32 slots (slot = sl*8+ks); wave w stages col-16-tile sl=w
    #pragma unroll
    for (int jj = 0; jj < 8; ++jj)
        gload16(zb + (size_t)(cbase + w * 16 + lr) * DD + jj * 32 + lg * 8,
                tile + (w * 8 + jj) * 512);

    // A fragments: 2 row-tiles x 8 k-slices (64 VGPR), PINNED resident
    bf16x8 aF[2][8];
    #pragma unroll
    for (int rt = 0; rt < 2; ++rt) {
        const unsigned short* ap = zb + (size_t)(rbase + rt * 16 + lr) * DD + lg * 8;
        #pragma unroll
        for (int ks = 0; ks < 8; ++ks) aF[rt][ks] = *(const bf16x8*)(ap + ks * 32);
    }
    #pragma unroll
    for (int rt = 0; rt < 2; ++rt)
        #pragma unroll
        for (int ks = 0; ks < 8; ++ks) pin16(aF[rt][ks]);

    float rs[2][4];
    #pragma unroll
    for (int rt = 0; rt < 2; ++rt)
        #pragma unroll
        for (int j = 0; j < 4; ++j) rs[rt][j] = 0.f;
    float cs[4];
    #pragma unroll
    for (int sl = 0; sl < 4; ++sl) cs[sl] = 0.f;

    __syncthreads();                                        // single staging drain

    #pragma unroll
    for (int sl = 0; sl < 4; ++sl) {
        f32x4 acc[2];
        acc[0] = (f32x4){0.f, 0.f, 0.f, 0.f};
        acc[1] = (f32x4){0.f, 0.f, 0.f, 0.f};
        #pragma unroll
        for (int ks = 0; ks < 8; ++ks) {
            bf16x8 bF = *(const bf16x8*)(tile + (sl * 8 + ks) * 512 + l * 8);
            acc[0] = __builtin_amdgcn_mfma_f32_16x16x32_bf16(aF[0][ks], bF, acc[0], 0, 0, 0);
            acc[1] = __builtin_amdgcn_mfma_f32_16x16x32_bf16(aF[1][ks], bF, acc[1], 0, 0, 0);
        }
        const int ci_u = cj * 4 + sl;
        #pragma unroll
        for (int rt = 0; rt < 2; ++rt) {
            const bool dt = (!mirror) && (ri_u0 + rt == ci_u);
            #pragma unroll
            for (int j = 0; j < 4; ++j) {
                float e = exp2_raw(acc[rt][j] - M_FIX);
                if (dt && (lr == lg * 4 + j)) e = 0.f;      // mask i==j
                rs[rt][j] += e;
                cs[sl] += e;
            }
        }
    }

    // row sums: reduce over 16 lanes sharing lg; lr==0 lanes write
    #pragma unroll
    for (int rt = 0; rt < 2; ++rt)
        #pragma unroll
        for (int j = 0; j < 4; ++j) {
            float v = rs[rt][j];
            v += __shfl_xor(v, 1, 64);
            v += __shfl_xor(v, 2, 64);
            v += __shfl_xor(v, 4, 64);
            v += __shfl_xor(v, 8, 64);
            rs[rt][j] = v;
        }
    if (lr == 0) {
        #pragma unroll
        for (int rt = 0; rt < 2; ++rt)
            #pragma unroll
            for (int j = 0; j < 4; ++j)
                PT[(size_t)cj * NN + rbase + rt * 16 + lg * 4 + j] = f2bf(rs[rt][j]);
    }

    // mirror column sums -> slot 2*rg (strictly-above blocks only; block-uniform)
    if (mirror) {
        #pragma unroll
        for (int sl = 0; sl < 4; ++sl) {
            float v = cs[sl];
            v += __shfl_xor(v, 16, 64);
            v += __shfl_xor(v, 32, 64);
            cs[sl] = v;                                     // sum over wave's 32 rows
        }
        __syncthreads();                                    // all tile reads done
        float* red = (float*)tile;                          // [4][64] floats = 1 KB
        if (lg == 0) {
            #pragma unroll
            for (int sl = 0; sl < 4; ++sl) red[w * 64 + sl * 16 + lr] = cs[sl];
        }
        __syncthreads();
        if (tid < 64) {
            const float v = red[tid] + red[64 + tid] + red[128 + tid] + red[192 + tid];
            PT[(size_t)(2 * rg) * NN + cbase + tid] = f2bf(v);
        }
    }
}

// ------------- Kernel 3: per-row masked-slot sum + pos subtraction -----------
// slot s valid for row r (rg = r>>7) iff (s >= 2rg) || s even — provably the
// exact set of slots simlse writes for this row. Branch-free select.
__global__ __launch_bounds__(128) void rowmerge_kernel(const unsigned short* __restrict__ PT,
                                                       const float* __restrict__ pos,
                                                       float* __restrict__ partial) {
    const int r = blockIdx.x * 128 + threadIdx.x;           // grid 64 -> r < 8192
    const int rg = r >> 7;
    float S = 0.f;
    #pragma unroll
    for (int s = 0; s < NCJ; ++s) {
        const float v = bf2f(PT[(size_t)s * NN + r]);
        const bool valid = (s >= 2 * rg) || ((s & 1) == 0);
        S += valid ? v : 0.f;
    }
    float val = M_FIX * LN2 + logf(S);                      // natural-domain lse
    if (r < B_ROWS) val -= 2.0f * pos[r];                   // both halves' pos
    __shared__ float red[128];
    red[threadIdx.x] = val;
    __syncthreads();
    for (int st = 64; st > 0; st >>= 1) {
        if (threadIdx.x < st) red[threadIdx.x] += red[threadIdx.x + st];
        __syncthreads();
    }
    if (threadIdx.x == 0) partial[blockIdx.x] = red[0];
}

// ------------- Kernel 4: final scalar ----------------------------------------
__global__ void final_kernel(const float* __restrict__ partial, float* __restrict__ out) {
    float v = partial[threadIdx.x];                         // block = 64 = grid of k3
    #pragma unroll
    for (int off = 32; off > 0; off >>= 1) v += __shfl_down(v, off, 64);
    if (threadIdx.x == 0) out[0] = v / (8192.f * 8192.f);
}

extern "C" void kernel_launch(void* const* d_in, const int* in_sizes, int n_in,
                              void* d_out, int out_size, void* d_ws, size_t ws_size,
                              hipStream_t stream) {
    const float* zi = (const float*)d_in[0];
    const float* zj = (const float*)d_in[1];
    float* out = (float*)d_out;
    char* ws = (char*)d_ws;

    unsigned short* zb = (unsigned short*)ws;                         // 4 MB
    unsigned short* PT = (unsigned short*)(ws + (size_t)NN * DD * 2); // 2 MB bf16 [128][NN]
    float* pos     = (float*)(ws + (size_t)NN * DD * 2 + (size_t)NCJ * NN * 2);  // 16 KB
    float* partial = pos + B_ROWS;                                    // 256 B

    hipLaunchKernelGGL(cast_pos_kernel, dim3(B_ROWS / 4), dim3(256), 0, stream, zi, zj, zb, pos);
    hipLaunchKernelGGL(simlse_kernel,   dim3(NBLK), dim3(256), 0, stream, zb, PT);
    hipLaunchKernelGGL(rowmerge_kernel, dim3(NN / 128), dim3(128), 0, stream, PT, pos, partial);
    hipLaunchKernelGGL(final_kernel,    dim3(1), dim3(64), 0, stream, partial, out);
}

// Round 11
// 65.201 us; speedup vs baseline: 1.0348x; 1.0339x over previous
//
#include <hip/hip_runtime.h>
#include <hip/hip_bf16.h>

#define DD 256
#define NN 8192
#define B_ROWS 4096
#define NRG 64                 // row-groups of 128
#define NCJ 128                // col-chunks of 64
#define NBLK 4160              // sum_{rg=0}^{63} (128 - 2*rg)
#define M_FIX 160.0f           // fixed softmax offset (exp2 domain)
#define SCALE 1.6986436f       // sqrt(2*log2(e)): sim lands in exp2 domain
#define LN2 0.69314718055994531f

typedef __attribute__((ext_vector_type(8))) short bf16x8;
typedef __attribute__((ext_vector_type(4))) float f32x4;

__device__ __forceinline__ unsigned short f2bf(float f) {
    unsigned int x = __float_as_uint(f);
    x += 0x7fffu + ((x >> 16) & 1u);   // RNE
    return (unsigned short)(x >> 16);
}
__device__ __forceinline__ float bf2f(unsigned short u) {
    return __uint_as_float((unsigned int)u << 16);
}
__device__ __forceinline__ float exp2_raw(float x) {
    float r; asm("v_exp_f32 %0, %1" : "=v"(r) : "v"(x)); return r;
}
__device__ __forceinline__ void gload16(const unsigned short* g, unsigned short* l) {
    __builtin_amdgcn_global_load_lds(
        (const __attribute__((address_space(1))) void*)g,
        (__attribute__((address_space(3))) void*)l, 16, 0, 0);
}

// ------------- Kernel 1: fused cast(z*SCALE -> bf16) + pos dot (fp32) --------
__global__ void cast_pos_kernel(const float* __restrict__ zi, const float* __restrict__ zj,
                                unsigned short* __restrict__ zb, float* __restrict__ pos) {
    const int w = threadIdx.x >> 6;
    const int l = threadIdx.x & 63;
    const int r = blockIdx.x * 4 + w;                       // grid 1024 -> r < 4096
    const float4 a = ((const float4*)(zi + (size_t)r * DD))[l];
    const float4 b = ((const float4*)(zj + (size_t)r * DD))[l];
    float d = a.x * b.x + a.y * b.y + a.z * b.z + a.w * b.w;
    #pragma unroll
    for (int off = 32; off > 0; off >>= 1) d += __shfl_down(d, off, 64);
    if (l == 0) pos[r] = 2.0f * d;                          // natural-domain pos logit
    ushort4 oa, ob;
    oa.x = f2bf(a.x * SCALE); oa.y = f2bf(a.y * SCALE);
    oa.z = f2bf(a.z * SCALE); oa.w = f2bf(a.w * SCALE);
    ob.x = f2bf(b.x * SCALE); ob.y = f2bf(b.y * SCALE);
    ob.z = f2bf(b.z * SCALE); ob.w = f2bf(b.w * SCALE);
    ((ushort4*)(zb + (size_t)r * DD))[l] = oa;
    ((ushort4*)(zb + (size_t)(r + B_ROWS) * DD))[l] = ob;
}

// ------------- Kernel 2: symmetric Gram + fixed-M exp2 sums ------------------
// OCCUPANCY-FIRST (10-round lesson: LDS-busy scales linearly with resident
// waves; round 2's 20-wave/CU config is the only one that ever hit ~66% LDS
// efficiency). Geometry: 4160 rect blocks (rg: 128 rows) x (cj: 64 cols),
// cj >= 2*rg; 512 thr = 8 waves; wave owns 16 rows (aF[8] ~ 32 VGPR, R=1);
// __launch_bounds__(512,8) pins allocation <=64 regs like round 2 (VGPR=32).
// 32 KB B-panel staged once in fragment order, one barrier in main path.
// PT bf16 [128][NN]: row partials at PT[cj][row], mirror at PT[2rg][col].
__global__ __launch_bounds__(512, 8) void simlse_kernel(const unsigned short* __restrict__ zb,
                                                        unsigned short* __restrict__ PT) {
    __shared__ unsigned short tile[32 * 512];               // 32 KB: 32 slots x 1 KB
    const int tid = threadIdx.x;
    const int w  = tid >> 6;        // 0..7
    const int l  = tid & 63;
    const int lg = l >> 4;          // 0..3
    const int lr = l & 15;          // 0..15

    // XCD-aware bijective swizzle (4160 = 8 x 520)
    const int wg = ((int)blockIdx.x & 7) * (NBLK / 8) + ((int)blockIdx.x >> 3);
    int b = wg, rg = 0;
    while (b >= NCJ - 2 * rg) { b -= NCJ - 2 * rg; ++rg; }
    const int cj = 2 * rg + b;
    const bool mirror = (cj >= 2 * rg + 2);                 // block-uniform
    const int rbase = rg * 128 + w * 16;                    // wave's 16 rows
    const int cbase = cj * 64;
    const int ri_u  = rg * 8 + w;                           // wave's row 16-tile idx

    // stage panel: 32 slots (slot = sl*8+ks); wave w stages 4 slots
    #pragma unroll
    for (int jj = 0; jj < 4; ++jj) {
        const int slot = w * 4 + jj, sl = slot >> 3, ks = slot & 7;
        gload16(zb + (size_t)(cbase + sl * 16 + lr) * DD + ks * 32 + lg * 8,
                tile + slot * 512);
    }

    // A fragments: 8 k-slices for the wave's 16 rows (~32 VGPR)
    bf16x8 aF[8];
    {
        const unsigned short* ap = zb + (size_t)(rbase + lr) * DD + lg * 8;
        #pragma unroll
        for (int ks = 0; ks < 8; ++ks) aF[ks] = *(const bf16x8*)(ap + ks * 32);
    }

    float rs[4] = {0.f, 0.f, 0.f, 0.f};
    float cs[4] = {0.f, 0.f, 0.f, 0.f};

    __syncthreads();                                        // single staging drain

    #pragma unroll
    for (int sl = 0; sl < 4; ++sl) {
        f32x4 acc = (f32x4){0.f, 0.f, 0.f, 0.f};
        #pragma unroll
        for (int ks = 0; ks < 8; ++ks) {
            bf16x8 bF = *(const bf16x8*)(tile + (sl * 8 + ks) * 512 + l * 8);
            acc = __builtin_amdgcn_mfma_f32_16x16x32_bf16(aF[ks], bF, acc, 0, 0, 0);
        }
        const bool dt = (!mirror) && (ri_u == cj * 4 + sl);
        #pragma unroll
        for (int j = 0; j < 4; ++j) {
            float e = exp2_raw(acc[j] - M_FIX);
            if (dt && (lr == lg * 4 + j)) e = 0.f;          // mask i==j
            rs[j] += e;
            cs[sl] += e;
        }
    }

    // row sums: reduce over 16 lanes sharing lg; lr==0 lanes write
    #pragma unroll
    for (int j = 0; j < 4; ++j) {
        float v = rs[j];
        v += __shfl_xor(v, 1, 64);
        v += __shfl_xor(v, 2, 64);
        v += __shfl_xor(v, 4, 64);
        v += __shfl_xor(v, 8, 64);
        rs[j] = v;
    }
    if (lr == 0) {
        #pragma unroll
        for (int j = 0; j < 4; ++j)
            PT[(size_t)cj * NN + rbase + lg * 4 + j] = f2bf(rs[j]);
    }

    // mirror column sums -> slot 2*rg (strictly-above blocks only; block-uniform)
    if (mirror) {
        #pragma unroll
        for (int sl = 0; sl < 4; ++sl) {
            float v = cs[sl];
            v += __shfl_xor(v, 16, 64);
            v += __shfl_xor(v, 32, 64);
            cs[sl] = v;                                     // sum over wave's 16 rows
        }
        __syncthreads();                                    // all tile reads done
        float* red = (float*)tile;                          // [8][64] floats = 2 KB
        if (lg == 0) {
            #pragma unroll
            for (int sl = 0; sl < 4; ++sl) red[w * 64 + sl * 16 + lr] = cs[sl];
        }
        __syncthreads();
        if (tid < 64) {
            float v = 0.f;
            #pragma unroll
            for (int ww = 0; ww < 8; ++ww) v += red[ww * 64 + tid];
            PT[(size_t)(2 * rg) * NN + cbase + tid] = f2bf(v);
        }
    }
}

// ------------- Kernel 3: per-row masked-slot sum + pos subtraction -----------
// 8 lanes per row (16 slots each), shfl-combine, 256 blocks for latency
// coverage. Slot s valid for row r (rg=r>>7) iff (s >= 2rg) || s even —
// provably the exact set of slots simlse writes for this row.
__global__ __launch_bounds__(256) void rowmerge_kernel(const unsigned short* __restrict__ PT,
                                                       const float* __restrict__ pos,
                                                       float* __restrict__ partial) {
    const int tid = threadIdx.x;
    const int rloc = tid >> 3;                              // 0..31
    const int sg   = tid & 7;                               // 0..7
    const int r  = blockIdx.x * 32 + rloc;                  // grid 256 -> r < 8192
    const int rg = r >> 7;                                  // block-uniform (32 < 128)
    float S = 0.f;
    #pragma unroll
    for (int k = 0; k < 16; ++k) {
        const int s = sg * 16 + k;
        const float v = bf2f(PT[(size_t)s * NN + r]);
        const bool valid = (s >= 2 * rg) || ((s & 1) == 0);
        S += valid ? v : 0.f;
    }
    S += __shfl_xor(S, 1, 64);
    S += __shfl_xor(S, 2, 64);
    S += __shfl_xor(S, 4, 64);
    __shared__ float red[32];
    if (sg == 0) {
        float val = M_FIX * LN2 + logf(S);                  // natural-domain lse
        if (r < B_ROWS) val -= 2.0f * pos[r];               // both halves' pos
        red[rloc] = val;
    }
    __syncthreads();
    if (tid < 32) {
        float v = red[tid];
        v += __shfl_xor(v, 1, 64);
        v += __shfl_xor(v, 2, 64);
        v += __shfl_xor(v, 4, 64);
        v += __shfl_xor(v, 8, 64);
        v += __shfl_xor(v, 16, 64);
        if (tid == 0) partial[blockIdx.x] = v;
    }
}

// ------------- Kernel 4: final scalar ----------------------------------------
__global__ __launch_bounds__(256) void final_kernel(const float* __restrict__ partial,
                                                    float* __restrict__ out) {
    const int tid = threadIdx.x;
    float v = partial[tid];                                 // 256 partials
    #pragma unroll
    for (int off = 32; off > 0; off >>= 1) v += __shfl_down(v, off, 64);
    __shared__ float red[4];
    if ((tid & 63) == 0) red[tid >> 6] = v;
    __syncthreads();
    if (tid == 0) out[0] = (red[0] + red[1] + red[2] + red[3]) / (8192.f * 8192.f);
}

extern "C" void kernel_launch(void* const* d_in, const int* in_sizes, int n_in,
                              void* d_out, int out_size, void* d_ws, size_t ws_size,
                              hipStream_t stream) {
    const float* zi = (const float*)d_in[0];
    const float* zj = (const float*)d_in[1];
    float* out = (float*)d_out;
    char* ws = (char*)d_ws;

    unsigned short* zb = (unsigned short*)ws;                         // 4 MB
    unsigned short* PT = (unsigned short*)(ws + (size_t)NN * DD * 2); // 2 MB bf16 [128][NN]
    float* pos     = (float*)(ws + (size_t)NN * DD * 2 + (size_t)NCJ * NN * 2);  // 16 KB
    float* partial = pos + B_ROWS;                                    // 1 KB

    hipLaunchKernelGGL(cast_pos_kernel, dim3(B_ROWS / 4), dim3(256), 0, stream, zi, zj, zb, pos);
    hipLaunchKernelGGL(simlse_kernel,   dim3(NBLK), dim3(512), 0, stream, zb, PT);
    hipLaunchKernelGGL(rowmerge_kernel, dim3(NN / 32), dim3(256), 0, stream, PT, pos, partial);
    hipLaunchKernelGGL(final_kernel,    dim3(1), dim3(256), 0, stream, partial, out);
}

// Round 13
// 63.962 us; speedup vs baseline: 1.0548x; 1.0194x over previous
//
#include <hip/hip_runtime.h>
#include <hip/hip_bf16.h>

#define DD 256
#define NN 8192
#define B_ROWS 4096
#define NBC 16                 // 16 column chunks of 512
#define NBLK 1024              // 64 row-blocks (128 rows) x 16 col-chunks
#define GSTR 8192              // zf group stride in SHORTS (32 rows x 256 k)
#define M_FIX 160.0f           // fixed softmax offset (exp2 domain)
#define SCALE 1.6986436f       // sqrt(2*log2(e)): sim lands in exp2 domain
#define LN2 0.69314718055994531f

typedef __attribute__((ext_vector_type(8)))  short bf16x8;
typedef __attribute__((ext_vector_type(16))) float f32x16;

__device__ __forceinline__ unsigned short f2bf(float f) {
    unsigned int x = __float_as_uint(f);
    x += 0x7fffu + ((x >> 16) & 1u);   // RNE
    return (unsigned short)(x >> 16);
}
__device__ __forceinline__ float exp2_raw(float x) {
    float r; asm("v_exp_f32 %0, %1" : "=v"(r) : "v"(x)); return r;
}
__device__ __forceinline__ void gload16(const unsigned short* g, unsigned short* l) {
    __builtin_amdgcn_global_load_lds(
        (const __attribute__((address_space(1))) void*)g,
        (__attribute__((address_space(3))) void*)l, 16, 0, 0);
}

// zf layout (bf16, fragment-major for mfma_32x32x16): group g = row/32 (stride
// GSTR=8192 shorts), k-slice ks = k/16 (slot = 512 shorts). Lane l holds row
// g*32+(l&31), k = ks*16 + (l>>5)*8 + j, at zf[g*GSTR + ks*512 + l*8 + j].
// (Round-12 NaN: stride was 16384 = the BYTE size -> layout spanned 8MB,
// aliased PT/pos. All users now GSTR.)

// ------------- Kernel 1: cast z*SCALE -> bf16 in zf fragment-major layout ----
__global__ __launch_bounds__(256) void cast_kernel(const float* __restrict__ zi,
                                                   const float* __restrict__ zj,
                                                   unsigned short* __restrict__ zf) {
    const int t = blockIdx.x * 256 + threadIdx.x;   // 262144 tasks = 8192 rows x 32
    const int r   = t >> 5;
    const int sub = t & 31;
    const int ks  = sub >> 1;
    const int hi  = sub & 1;
    const float* src = (r < B_ROWS ? zi + (size_t)r * DD
                                   : zj + (size_t)(r - B_ROWS) * DD) + ks * 16 + hi * 8;
    const float4 v0 = ((const float4*)src)[0];
    const float4 v1 = ((const float4*)src)[1];
    bf16x8 o;
    o[0] = (short)f2bf(v0.x * SCALE); o[1] = (short)f2bf(v0.y * SCALE);
    o[2] = (short)f2bf(v0.z * SCALE); o[3] = (short)f2bf(v0.w * SCALE);
    o[4] = (short)f2bf(v1.x * SCALE); o[5] = (short)f2bf(v1.y * SCALE);
    o[6] = (short)f2bf(v1.z * SCALE); o[7] = (short)f2bf(v1.w * SCALE);
    *(bf16x8*)(zf + (size_t)(r >> 5) * GSTR + ks * 512 + ((hi << 5) | (r & 31)) * 8) = o;
}

// ------------- Kernel 2: pos_r = 2*dot(z_i[r], z_j[r]) fp32 ------------------
__global__ __launch_bounds__(256) void pos_kernel(const float* __restrict__ zi,
                                                  const float* __restrict__ zj,
                                                  float* __restrict__ pos) {
    const int w = threadIdx.x >> 6;
    const int l = threadIdx.x & 63;
    const int r = blockIdx.x * 4 + w;                       // grid 1024 -> r < 4096
    const float4 a = ((const float4*)(zi + (size_t)r * DD))[l];
    const float4 b = ((const float4*)(zj + (size_t)r * DD))[l];
    float d = a.x * b.x + a.y * b.y + a.z * b.z + a.w * b.w;
    #pragma unroll
    for (int off = 32; off > 0; off >>= 1) d += __shfl_down(d, off, 64);
    if (l == 0) pos[r] = 2.0f * d;
}

// ------------- Kernel 3: full Gram via mfma_32x32x16 + fixed-M exp2 row sums --
// 1024 blocks = 64 row-blocks (128 rows) x 16 col-chunks (512 cols). EXACTLY
// 4 blocks/CU -> whole grid co-resident (32KB LDS); barrier drains overlap
// across blocks. 256 thr = 4 waves; wave owns 32 rows (one 32x32 MFMA row).
// 8 sequential 64-col tiles (32KB, fragment-order slots), 2 barriers each.
// 32x32x16 halves B LDS-bytes/output vs 16x16x32.
// PT fp32 [16][NN]: PT[bc][row] = sum over this block's 512 cols.
__global__ __launch_bounds__(256, 4) void simlse_kernel(const unsigned short* __restrict__ zf,
                                                        float* __restrict__ PT) {
    __shared__ unsigned short tile[32 * 512];               // 32 slots x 1KB = 32KB
    const int tid = threadIdx.x;
    const int w   = tid >> 6;       // 0..3
    const int l   = tid & 63;
    const int hi  = l >> 5;         // 0..1
    const int c31 = l & 31;         // 0..31

    // XCD swizzle: 1024 = 8 x 128; same-XCD blocks share a row-panel range
    const int wg = ((int)blockIdx.x & 7) * (NBLK / 8) + ((int)blockIdx.x >> 3);
    const int br = wg >> 4;         // 0..63
    const int bc = wg & 15;         // 0..15
    const int grp_r = br * 4 + w;   // wave's 32-row group
    const unsigned short* abase = zf + (size_t)grp_r * GSTR + l * 8;

    float rs[16];
    #pragma unroll
    for (int g = 0; g < 16; ++g) rs[g] = 0.f;

    for (int t = 0; t < 8; ++t) {
        __syncthreads();                                    // prev tile reads done
        // stage 64 cols = 2 col-groups x 16 ks-slots; wave w fills 8 slots
        #pragma unroll
        for (int jj = 0; jj < 8; ++jj) {
            const int slot = w * 8 + jj;                    // slot = ct*16 + ks
            const int gc = bc * 16 + t * 2 + (slot >> 4);
            gload16(zf + (size_t)gc * GSTR + (slot & 15) * 512 + l * 8,
                    tile + slot * 512);
        }
        __syncthreads();                                    // staging drained

        #pragma unroll
        for (int ct = 0; ct < 2; ++ct) {
            const int gc = bc * 16 + t * 2 + ct;
            f32x16 acc = {0.f,0.f,0.f,0.f,0.f,0.f,0.f,0.f,
                          0.f,0.f,0.f,0.f,0.f,0.f,0.f,0.f};
            #pragma unroll
            for (int ks = 0; ks < 16; ++ks) {
                bf16x8 aF = *(const bf16x8*)(abase + ks * 512);
                bf16x8 bF = *(const bf16x8*)(tile + (ct * 16 + ks) * 512 + l * 8);
                acc = __builtin_amdgcn_mfma_f32_32x32x16_bf16(aF, bF, acc, 0, 0, 0);
            }
            const bool dt = (grp_r == gc);                  // wave-uniform
            #pragma unroll
            for (int g = 0; g < 16; ++g) {
                float e = exp2_raw(acc[g] - M_FIX);
                // C/D: col = lane&31, row = (reg&3) + 8*(reg>>2) + 4*(lane>>5)
                if (dt && (c31 == ((g & 3) + 8 * (g >> 2) + 4 * hi))) e = 0.f;
                rs[g] += e;
            }
        }
    }

    // row sums: reduce each reg over the 32 lanes of its half; writer lane
    // is the one whose col index equals the reg's row index.
    #pragma unroll
    for (int g = 0; g < 16; ++g) {
        float v = rs[g];
        v += __shfl_xor(v, 1, 64);
        v += __shfl_xor(v, 2, 64);
        v += __shfl_xor(v, 4, 64);
        v += __shfl_xor(v, 8, 64);
        v += __shfl_xor(v, 16, 64);
        const int rl = (g & 3) + 8 * (g >> 2) + 4 * hi;
        if (c31 == rl)
            PT[(size_t)bc * NN + grp_r * 32 + rl] = v;
    }
}

// ------------- Kernel 4: per-row sum of 16 slots + pos subtraction -----------
__global__ __launch_bounds__(256) void rowmerge_kernel(const float* __restrict__ PT,
                                                       const float* __restrict__ pos,
                                                       float* __restrict__ partial) {
    const int r = blockIdx.x * 256 + threadIdx.x;           // grid 32 -> r < 8192
    float S = 0.f;
    #pragma unroll
    for (int s = 0; s < NBC; ++s) S += PT[(size_t)s * NN + r];  // coalesced
    float val = M_FIX * LN2 + logf(S);                      // natural-domain lse
    if (r < B_ROWS) val -= 2.0f * pos[r];                   // both halves' pos
    __shared__ float red[256];
    red[threadIdx.x] = val;
    __syncthreads();
    for (int st = 128; st > 0; st >>= 1) {
        if (threadIdx.x < st) red[threadIdx.x] += red[threadIdx.x + st];
        __syncthreads();
    }
    if (threadIdx.x == 0) partial[blockIdx.x] = red[0];
}

// ------------- Kernel 5: final scalar ----------------------------------------
__global__ void final_kernel(const float* __restrict__ partial, float* __restrict__ out) {
    float v = (threadIdx.x < 32) ? partial[threadIdx.x] : 0.f;
    #pragma unroll
    for (int off = 32; off > 0; off >>= 1) v += __shfl_down(v, off, 64);
    if (threadIdx.x == 0) out[0] = v / (8192.f * 8192.f);
}

extern "C" void kernel_launch(void* const* d_in, const int* in_sizes, int n_in,
                              void* d_out, int out_size, void* d_ws, size_t ws_size,
                              hipStream_t stream) {
    const float* zi = (const float*)d_in[0];
    const float* zj = (const float*)d_in[1];
    float* out = (float*)d_out;
    char* ws = (char*)d_ws;

    unsigned short* zf = (unsigned short*)ws;                      // 4 MB fragment-major
    float* PT      = (float*)(ws + (size_t)NN * DD * 2);           // 512 KB fp32 [16][NN]
    float* pos     = (float*)(ws + (size_t)NN * DD * 2 + (size_t)NBC * NN * 4);  // 16 KB
    float* partial = pos + B_ROWS;                                 // 128 B

    hipLaunchKernelGGL(cast_kernel,     dim3(NN * 32 / 256), dim3(256), 0, stream, zi, zj, zf);
    hipLaunchKernelGGL(pos_kernel,      dim3(B_ROWS / 4),    dim3(256), 0, stream, zi, zj, pos);
    hipLaunchKernelGGL(simlse_kernel,   dim3(NBLK),          dim3(256), 0, stream, zf, PT);
    hipLaunchKernelGGL(rowmerge_kernel, dim3(NN / 256),      dim3(256), 0, stream, PT, pos, partial);
    hipLaunchKernelGGL(final_kernel,    dim3(1),             dim3(64),  0, stream, partial, out);
}